// Round 11
// baseline (263.646 us; speedup 1.0000x reference)
//
#include <hip/hip_runtime.h>

// KCenterSampler FPS — dual-path sync with ASYMMETRIC polling.
// Round-9 lesson: dual_load waited vmcnt(0) on BOTH fast (L2) and slow (LLC)
// loads, so the poll period was pinned at LLC latency (~900cy) even though
// the fast slot had the key. This round: spin on the fast slot only
// (sc0, local-XCD L2, ~250cy period); every 4th iteration lanes still at
// zero also check the slow slot (sc0 sc1, LLC). Slow slot is polled
// infinitely often + agent-scope publish always lands there -> guaranteed
// progress for ANY block->XCD mapping (no deadlock by construction).
//
// Everything else byte-identical to round 9 (passed, absmax 0):
// 8 segments × 16 blocks cooperative, segment = bid&7 (round-robin -> same
// XCD), coords/sq/dist in VGPRs (waves_per_eu(1,1) + asm launder, VGPR=132),
// packed (monotone-dist, NPTS-j) u64 keys, first-index tie-break.

#define NPTS 6272
#define CDIM 35
#define BT   8
#define KSEL 128
#define THW  12544
#define BPS  16                  // blocks per segment
#define PPB  392                 // points per block
#define BLK  256
#define NB   (BT * BPS)          // 128 blocks
#define TAILN (PPB - BLK)        // 136: threads owning a 2nd point

__device__ __forceinline__ unsigned long long key_of(float v, int j) {
  unsigned int u = __float_as_uint(v);
  u = (u & 0x80000000u) ? ~u : (u | 0x80000000u);   // monotone float->uint
  return ((unsigned long long)u << 32) | (unsigned int)(NPTS - j); // low!=0
}
__device__ __forceinline__ unsigned long long kmax(unsigned long long a,
                                                   unsigned long long b) {
  return a > b ? a : b;
}

// publish to both paths: fast = sc0 (local-XCD L2 write-through),
// slow = agent scope (LLC, proven visible cross-XCD).
__device__ __forceinline__ void dual_store(unsigned long long* fp,
                                           unsigned long long* sp,
                                           unsigned long long v) {
  asm volatile("global_store_dwordx2 %0, %1, off sc0"
               :: "v"(fp), "v"(v) : "memory");
  __hip_atomic_store(sp, v, __ATOMIC_RELAXED, __HIP_MEMORY_SCOPE_AGENT);
}

// "=&v" early-clobber REQUIRED: without it the result may alias the address
// pair (round-6 hang).
__device__ __forceinline__ unsigned long long load_fast(const unsigned long long* p) {
  unsigned long long r;
  asm volatile("global_load_dwordx2 %0, %1, off sc0\n\t"
               "s_waitcnt vmcnt(0)"
               : "=&v"(r) : "v"(p) : "memory");
  return r;
}
__device__ __forceinline__ unsigned long long load_slow(const unsigned long long* p) {
  unsigned long long r;
  asm volatile("global_load_dwordx2 %0, %1, off sc0 sc1\n\t"
               "s_waitcnt vmcnt(0)"
               : "=&v"(r) : "v"(p) : "memory");
  return r;
}

__global__ __attribute__((amdgpu_waves_per_eu(1, 1))) __launch_bounds__(BLK)
void fps_kernel(const float* __restrict__ x,
                const int* __restrict__ init_,
                int* __restrict__ out_idx,
                unsigned long long* __restrict__ slow_slots,
                unsigned long long* __restrict__ fast_slots) {
  __shared__ unsigned long long wk[4];
  __shared__ int far_s;

  const int bid  = (int)blockIdx.x;
  const int b    = bid & 7;            // segment: round-robin -> same XCD
  const int sub  = bid >> 3;           // sub-block 0..15 within segment
  const int tid  = (int)threadIdx.x;
  const int lane = tid & 63;
  const int wid  = tid >> 6;
  const int j0   = sub * PPB;
  const float* xg = x + (size_t)b * NPTS * CDIM;
  unsigned long long* sseg = slow_slots + (size_t)b * KSEL * BPS;
  unsigned long long* fseg = fast_slots + (size_t)b * KSEL * BPS;

  // ---- one-time load: coords -> VGPRs (laundered), sq sequential ----
  float xr0[CDIM], xr1[CDIM];
  float sqr0, sqr1, df0, df1;
  {
    const float* src0 = xg + (size_t)(j0 + tid) * CDIM;
    float acc = 0.0f;
    {
#pragma clang fp contract(off)
#pragma unroll
      for (int c = 0; c < CDIM; ++c) { float v = src0[c]; xr0[c] = v; acc = acc + v * v; }
    }
    sqr0 = acc; df0 = 50000.0f;
    sqr1 = 0.0f; df1 = 50000.0f;
#pragma unroll
    for (int c = 0; c < CDIM; ++c) xr1[c] = 0.0f;
    if (tid < TAILN) {
      const float* src1 = xg + (size_t)(j0 + BLK + tid) * CDIM;
      float acc1 = 0.0f;
      {
#pragma clang fp contract(off)
#pragma unroll
        for (int c = 0; c < CDIM; ++c) { float v = src1[c]; xr1[c] = v; acc1 = acc1 + v * v; }
      }
      sqr1 = acc1;
    }
#pragma unroll
    for (int c = 0; c < CDIM; ++c) {
      asm volatile("" : "+v"(xr0[c]));
      asm volatile("" : "+v"(xr1[c]));
    }
    asm volatile("" : "+v"(sqr0));
    asm volatile("" : "+v"(sqr1));
  }

  int far;
  { int f = init_[b] % NPTS; if (f < 0) f += NPTS; far = f; }  // jnp.remainder
  if (sub == 0 && tid == 0) out_idx[b * KSEL] = far;

  // ---- 127 sequential FPS steps ----
  for (int step = 1; step < KSEL; ++step) {
    // farthest point's coords: uniform-address broadcast loads (L2-hit)
    const int fu = __builtin_amdgcn_readfirstlane(far);
    const float* fx = xg + (size_t)fu * CDIM;
    float xf[CDIM];
#pragma unroll
    for (int c = 0; c < CDIM; ++c) xf[c] = fx[c];

    // sqf: sequential chain from identical f32 values -> bitwise equal
    float sqf;
    {
#pragma clang fp contract(off)
      float a = 0.0f;
#pragma unroll
      for (int c = 0; c < CDIM; ++c) { float t = xf[c]; a = a + t * t; }
      sqf = a;
    }

    // point 0 (all threads)
    unsigned long long bk;
    {
      float dot = 0.0f;
#pragma unroll
      for (int c = 0; c < CDIM; ++c)
        dot = __builtin_fmaf(xf[c], xr0[c], dot);          // k-sequential FMA
      float d2;
      {
#pragma clang fp contract(off)
        d2 = (sqf + sqr0) - 2.0f * dot;                    // reference order
      }
      d2 = fmaxf(d2, 0.0f);
      float d = __fsqrt_rn(d2);
      const int j = j0 + tid;
      d = (j == far) ? -1.0f : d;                          // diagonal = -1
      float nd = fminf(d, df0);                            // f32 min-carry
      df0 = nd;
      bk = key_of(nd, j);
    }
    // point 1 (threads 0..135)
    if (tid < TAILN) {
      float dot = 0.0f;
#pragma unroll
      for (int c = 0; c < CDIM; ++c)
        dot = __builtin_fmaf(xf[c], xr1[c], dot);
      float d2;
      {
#pragma clang fp contract(off)
        d2 = (sqf + sqr1) - 2.0f * dot;
      }
      d2 = fmaxf(d2, 0.0f);
      float d = __fsqrt_rn(d2);
      const int j = j0 + BLK + tid;
      d = (j == far) ? -1.0f : d;
      float nd = fminf(d, df1);
      df1 = nd;
      bk = kmax(bk, key_of(nd, j));
    }

    // wave-level max of packed keys (order = (value, first-index))
#pragma unroll
    for (int off = 32; off > 0; off >>= 1)
      bk = kmax(bk, __shfl_down(bk, off));
    if (lane == 0) wk[wid] = bk;
    __syncthreads();                                       // barrier 1

    if (tid < BPS) {
      if (tid == 0) {
        unsigned long long m = kmax(kmax(wk[0], wk[1]), kmax(wk[2], wk[3]));
        dual_store(&fseg[step * BPS + sub], &sseg[step * BPS + sub], m);
      }
      asm volatile("" ::: "memory");   // keep stores ahead of the spin loop
      // asymmetric poll: spin on fast slot (local L2, ~250cy period);
      // every 4th retry, lanes still at zero also check the slow slot (LLC).
      unsigned long long k = 0ull;
      const unsigned long long* fp = &fseg[step * BPS + tid];
      const unsigned long long* sp = &sseg[step * BPS + tid];
      int it = 0;
      do {
        if (k == 0ull) k = load_fast(fp);
        if (k == 0ull && (it & 3) == 3) k = load_slow(sp);
        ++it;
      } while (__any(k == 0ull));
      // in-wave max over the 16 polled keys (lanes 0..15)
#pragma unroll
      for (int off = 8; off > 0; off >>= 1)
        k = kmax(k, __shfl_down(k, off));
      if (tid == 0) {
        int f = NPTS - (int)(unsigned int)(k & 0xFFFFFFFFull);
        far_s = f;
        if (sub == 0) out_idx[b * KSEL + step] = f;
      }
    }
    __syncthreads();                                       // barrier 2
    far = far_s;
  }
}

// ---------------------------------------------------------------------------
// gather patches (first 32 channels) + write indices (as f32)
// ---------------------------------------------------------------------------
__global__ __launch_bounds__(256) void gather_kernel(const float* __restrict__ x,
                                                     const int* __restrict__ out_idx,
                                                     float* __restrict__ patches,
                                                     float* __restrict__ sidx) {
  const int b = (int)blockIdx.x;     // 0..3
  const int m = (int)threadIdx.x;    // 0..255
  const int td = m >> 7;             // time segment 0/1
  const int i  = m & 127;
  const int li = out_idx[(b * 2 + td) * KSEL + i];
  const int gi = li + td * NPTS;
  sidx[b * 256 + m] = (float)gi;
  const float* src = x + ((size_t)b * THW + gi) * CDIM;
  float* dst = patches + ((size_t)b * 256 + m) * 32;
#pragma unroll
  for (int c = 0; c < 32; ++c) dst[c] = src[c];   // first C-3 channels
}

extern "C" void kernel_launch(void* const* d_in, const int* in_sizes, int n_in,
                              void* d_out, int out_size, void* d_ws, size_t ws_size,
                              hipStream_t stream) {
  const float* x    = (const float*)d_in[0];
  const int*   init = (const int*)d_in[1];
  (void)in_sizes; (void)n_in; (void)out_size; (void)ws_size;

  // ws layout: slow [BT*KSEL*BPS u64] | fast [BT*KSEL*BPS u64] | idx [ints]
  const size_t arr = (size_t)BT * KSEL * BPS * sizeof(unsigned long long);
  unsigned long long* slow_slots = (unsigned long long*)d_ws;
  unsigned long long* fast_slots = (unsigned long long*)((char*)d_ws + arr);
  int* idx = (int*)((char*)d_ws + 2 * arr);

  float* patches = (float*)d_out;
  float* sidx    = patches + (size_t)4 * 256 * 32;

  hipMemsetAsync(d_ws, 0, 2 * arr, stream);   // zero both slot arrays

  void* kargs[] = { (void*)&x, (void*)&init, (void*)&idx,
                    (void*)&slow_slots, (void*)&fast_slots };
  hipLaunchCooperativeKernel((const void*)fps_kernel, dim3(NB), dim3(BLK),
                             kargs, 0, stream);

  hipLaunchKernelGGL(gather_kernel, dim3(4), dim3(256), 0, stream,
                     x, idx, patches, sidx);
}

// Round 13
// 225.336 us; speedup vs baseline: 1.1700x; 1.1700x over previous
//
#include <hip/hip_runtime.h>

// KCenterSampler FPS — R9 structure + DPP reductions + depth-3 pipelined poll.
// (R11 resubmit: gfx950 asm requires `off offset:N sc0 sc1` — offset BEFORE
// cache flags; `off sc0 sc1 offset:N` does not assemble.)
//
// Model (r10 post-mortem): cross-XCD sc0 "fast path" never fires; R9's win was
// bid&7 co-locating each segment's 16 blocks on one XCD (xf broadcast becomes
// an L2 hit). Remaining per-step costs: shuffle reduces (~1150cy via bpermute)
// and the 900cy LLC poll period. Fixes:
//  1) wave/16-lane max via DPP (row_shr 1/2/4/8 + row_bcast 15/31), ~6x faster
//  2) poll loop with 3 outstanding lo/hi dword pairs, vmcnt(4) per stage,
//     v_max_u32 merge (slot words are write-once 0->nonzero, so max-merge and
//     per-word polling are exact; exit when min(lo,hi)!=0 on all lanes).
// Publish unchanged: agent-scope RELAXED u64 store (round-4-proven) -> the
// poll always terminates. Slots zeroed per launch by hipMemsetAsync.
// Coords/sq/dist in VGPRs (waves_per_eu(1,1) + asm launder, VGPR=132, r8).
// Arithmetic bit-identical to rounds 1/3/4/8/9 (absmax 0).

#define NPTS 6272
#define CDIM 35
#define BT   8
#define KSEL 128
#define THW  12544
#define BPS  16                  // blocks per segment
#define PPB  392                 // points per block
#define BLK  256
#define NB   (BT * BPS)          // 128 blocks
#define TAILN (PPB - BLK)        // 136: threads owning a 2nd point

__device__ __forceinline__ unsigned long long key_of(float v, int j) {
  unsigned int u = __float_as_uint(v);
  u = (u & 0x80000000u) ? ~u : (u | 0x80000000u);   // monotone float->uint
  return ((unsigned long long)u << 32) | (unsigned int)(NPTS - j); // both words !=0
}
__device__ __forceinline__ unsigned long long kmax(unsigned long long a,
                                                   unsigned long long b) {
  return a > b ? a : b;
}

// one DPP max step on a u64 key (both 32-bit halves moved with the same ctrl)
template <int CTRL, int RMASK, bool BC>
__device__ __forceinline__ unsigned long long dpp_kmax(unsigned long long k) {
  unsigned int lo = (unsigned int)k, hi = (unsigned int)(k >> 32);
  unsigned int tlo = (unsigned int)__builtin_amdgcn_update_dpp(0, (int)lo, CTRL, RMASK, 0xF, BC);
  unsigned int thi = (unsigned int)__builtin_amdgcn_update_dpp(0, (int)hi, CTRL, RMASK, 0xF, BC);
  unsigned long long t = ((unsigned long long)thi << 32) | tlo;
  return kmax(k, t);
}

// 64-lane max -> scalar (all lanes get result via readlane 63). Full-exec only.
__device__ __forceinline__ unsigned long long wave_kmax64(unsigned long long k) {
  k = dpp_kmax<0x111, 0xF, true >(k);   // row_shr:1
  k = dpp_kmax<0x112, 0xF, true >(k);   // row_shr:2
  k = dpp_kmax<0x114, 0xF, true >(k);   // row_shr:4
  k = dpp_kmax<0x118, 0xF, true >(k);   // row_shr:8   -> lanes 15/31/47/63 = row max
  k = dpp_kmax<0x142, 0xA, false>(k);   // row_bcast:15 -> lanes 31/63 fold prev row
  k = dpp_kmax<0x143, 0xC, false>(k);   // row_bcast:31 -> lane63 = wave max
  unsigned int rlo = (unsigned int)__builtin_amdgcn_readlane((int)(unsigned int)k, 63);
  unsigned int rhi = (unsigned int)__builtin_amdgcn_readlane((int)(k >> 32), 63);
  return ((unsigned long long)rhi << 32) | rlo;
}

// max over lanes 0..15 (exec = tid<16): row_shr within row 0, result lane 15.
__device__ __forceinline__ unsigned long long row16_kmax(unsigned long long k) {
  k = dpp_kmax<0x111, 0xF, true>(k);
  k = dpp_kmax<0x112, 0xF, true>(k);
  k = dpp_kmax<0x114, 0xF, true>(k);
  k = dpp_kmax<0x118, 0xF, true>(k);
  unsigned int rlo = (unsigned int)__builtin_amdgcn_readlane((int)(unsigned int)k, 15);
  unsigned int rhi = (unsigned int)__builtin_amdgcn_readlane((int)(k >> 32), 15);
  return ((unsigned long long)rhi << 32) | rlo;
}

// depth-3 pipelined LLC poll of one u64 slot (written once, 0 -> key).
// lo/hi polled as separate dwords; each word is write-once so v_max_u32
// merge is exact. Exit when min(klo,khi)!=0 on every active lane.
// All temps early-clobbered; drains vmcnt(0) on exit.
__device__ __forceinline__ unsigned long long poll_slot(const unsigned long long* p) {
  unsigned int klo = 0u, khi = 0u;
  unsigned int a0, b0, a1, b1, a2, b2, t;
  asm volatile(
      "global_load_dword %[a0], %[ad], off sc0 sc1\n\t"
      "global_load_dword %[b0], %[ad], off offset:4 sc0 sc1\n\t"
      "global_load_dword %[a1], %[ad], off sc0 sc1\n\t"
      "global_load_dword %[b1], %[ad], off offset:4 sc0 sc1\n\t"
      "global_load_dword %[a2], %[ad], off sc0 sc1\n\t"
      "global_load_dword %[b2], %[ad], off offset:4 sc0 sc1\n\t"
      "1:\n\t"
      "s_waitcnt vmcnt(4)\n\t"
      "v_max_u32 %[klo], %[klo], %[a0]\n\t"
      "v_max_u32 %[khi], %[khi], %[b0]\n\t"
      "global_load_dword %[a0], %[ad], off sc0 sc1\n\t"
      "global_load_dword %[b0], %[ad], off offset:4 sc0 sc1\n\t"
      "v_min_u32 %[t], %[klo], %[khi]\n\t"
      "v_cmp_eq_u32 vcc, 0, %[t]\n\t"
      "s_cbranch_vccz 9f\n\t"
      "s_waitcnt vmcnt(4)\n\t"
      "v_max_u32 %[klo], %[klo], %[a1]\n\t"
      "v_max_u32 %[khi], %[khi], %[b1]\n\t"
      "global_load_dword %[a1], %[ad], off sc0 sc1\n\t"
      "global_load_dword %[b1], %[ad], off offset:4 sc0 sc1\n\t"
      "v_min_u32 %[t], %[klo], %[khi]\n\t"
      "v_cmp_eq_u32 vcc, 0, %[t]\n\t"
      "s_cbranch_vccz 9f\n\t"
      "s_waitcnt vmcnt(4)\n\t"
      "v_max_u32 %[klo], %[klo], %[a2]\n\t"
      "v_max_u32 %[khi], %[khi], %[b2]\n\t"
      "global_load_dword %[a2], %[ad], off sc0 sc1\n\t"
      "global_load_dword %[b2], %[ad], off offset:4 sc0 sc1\n\t"
      "v_min_u32 %[t], %[klo], %[khi]\n\t"
      "v_cmp_eq_u32 vcc, 0, %[t]\n\t"
      "s_cbranch_vccnz 1b\n\t"
      "9:\n\t"
      "s_waitcnt vmcnt(0)"
      : [klo] "+v"(klo), [khi] "+v"(khi),
        [a0] "=&v"(a0), [b0] "=&v"(b0), [a1] "=&v"(a1), [b1] "=&v"(b1),
        [a2] "=&v"(a2), [b2] "=&v"(b2), [t] "=&v"(t)
      : [ad] "v"(p)
      : "vcc", "memory");
  return ((unsigned long long)khi << 32) | klo;
}

__global__ __attribute__((amdgpu_waves_per_eu(1, 1))) __launch_bounds__(BLK)
void fps_kernel(const float* __restrict__ x,
                const int* __restrict__ init_,
                int* __restrict__ out_idx,
                unsigned long long* __restrict__ slots) {
  __shared__ unsigned long long wk[4];
  __shared__ int far_s;

  const int bid  = (int)blockIdx.x;
  const int b    = bid & 7;            // segment: round-robin -> same XCD
  const int sub  = bid >> 3;           // sub-block 0..15 within segment
  const int tid  = (int)threadIdx.x;
  const int lane = tid & 63;
  const int wid  = tid >> 6;
  const int j0   = sub * PPB;
  const float* xg = x + (size_t)b * NPTS * CDIM;
  unsigned long long* seg = slots + (size_t)b * KSEL * BPS;

  // ---- one-time load: coords -> VGPRs (laundered), sq sequential ----
  float xr0[CDIM], xr1[CDIM];
  float sqr0, sqr1, df0, df1;
  {
    const float* src0 = xg + (size_t)(j0 + tid) * CDIM;
    float acc = 0.0f;
    {
#pragma clang fp contract(off)
#pragma unroll
      for (int c = 0; c < CDIM; ++c) { float v = src0[c]; xr0[c] = v; acc = acc + v * v; }
    }
    sqr0 = acc; df0 = 50000.0f;
    sqr1 = 0.0f; df1 = 50000.0f;
#pragma unroll
    for (int c = 0; c < CDIM; ++c) xr1[c] = 0.0f;
    if (tid < TAILN) {
      const float* src1 = xg + (size_t)(j0 + BLK + tid) * CDIM;
      float acc1 = 0.0f;
      {
#pragma clang fp contract(off)
#pragma unroll
        for (int c = 0; c < CDIM; ++c) { float v = src1[c]; xr1[c] = v; acc1 = acc1 + v * v; }
      }
      sqr1 = acc1;
    }
#pragma unroll
    for (int c = 0; c < CDIM; ++c) {
      asm volatile("" : "+v"(xr0[c]));
      asm volatile("" : "+v"(xr1[c]));
    }
    asm volatile("" : "+v"(sqr0));
    asm volatile("" : "+v"(sqr1));
  }

  int far;
  { int f = init_[b] % NPTS; if (f < 0) f += NPTS; far = f; }  // jnp.remainder
  if (sub == 0 && tid == 0) out_idx[b * KSEL] = far;

  // ---- 127 sequential FPS steps ----
  for (int step = 1; step < KSEL; ++step) {
    // farthest point's coords: uniform-address broadcast loads (L2-hit,
    // segment's 16 blocks share one XCD via bid&7)
    const int fu = __builtin_amdgcn_readfirstlane(far);
    const float* fx = xg + (size_t)fu * CDIM;
    float xf[CDIM];
#pragma unroll
    for (int c = 0; c < CDIM; ++c) xf[c] = fx[c];

    // sqf: sequential chain from identical f32 values -> bitwise equal
    float sqf;
    {
#pragma clang fp contract(off)
      float a = 0.0f;
#pragma unroll
      for (int c = 0; c < CDIM; ++c) { float t = xf[c]; a = a + t * t; }
      sqf = a;
    }

    // point 0 (all threads)
    unsigned long long bk;
    {
      float dot = 0.0f;
#pragma unroll
      for (int c = 0; c < CDIM; ++c)
        dot = __builtin_fmaf(xf[c], xr0[c], dot);          // k-sequential FMA
      float d2;
      {
#pragma clang fp contract(off)
        d2 = (sqf + sqr0) - 2.0f * dot;                    // reference order
      }
      d2 = fmaxf(d2, 0.0f);
      float d = __fsqrt_rn(d2);
      const int j = j0 + tid;
      d = (j == far) ? -1.0f : d;                          // diagonal = -1
      float nd = fminf(d, df0);                            // f32 min-carry
      df0 = nd;
      bk = key_of(nd, j);
    }
    // point 1 (threads 0..135)
    if (tid < TAILN) {
      float dot = 0.0f;
#pragma unroll
      for (int c = 0; c < CDIM; ++c)
        dot = __builtin_fmaf(xf[c], xr1[c], dot);
      float d2;
      {
#pragma clang fp contract(off)
        d2 = (sqf + sqr1) - 2.0f * dot;
      }
      d2 = fmaxf(d2, 0.0f);
      float d = __fsqrt_rn(d2);
      const int j = j0 + BLK + tid;
      d = (j == far) ? -1.0f : d;
      float nd = fminf(d, df1);
      df1 = nd;
      bk = kmax(bk, key_of(nd, j));
    }

    // wave max via DPP (full exec); every lane gets the wave max as scalar
    bk = wave_kmax64(bk);
    if (lane == 0) wk[wid] = bk;
    __syncthreads();                                       // barrier 1

    if (tid < BPS) {
      if (tid == 0) {
        unsigned long long m = kmax(kmax(wk[0], wk[1]), kmax(wk[2], wk[3]));
        // payload self-contained -> RELAXED agent scope (round-4-proven)
        __hip_atomic_store(&seg[step * BPS + sub], m,
                           __ATOMIC_RELAXED, __HIP_MEMORY_SCOPE_AGENT);
      }
      asm volatile("" ::: "memory");   // keep store ahead of the poll
      // pipelined poll of this lane's slot, then 16-lane DPP max
      unsigned long long k = poll_slot(&seg[step * BPS + tid]);
      k = row16_kmax(k);
      if (tid == 0) {
        int f = NPTS - (int)(unsigned int)(k & 0xFFFFFFFFull);
        far_s = f;
        if (sub == 0) out_idx[b * KSEL + step] = f;
      }
    }
    __syncthreads();                                       // barrier 2
    far = far_s;
  }
}

// ---------------------------------------------------------------------------
// gather patches (first 32 channels) + write indices (as f32)
// ---------------------------------------------------------------------------
__global__ __launch_bounds__(256) void gather_kernel(const float* __restrict__ x,
                                                     const int* __restrict__ out_idx,
                                                     float* __restrict__ patches,
                                                     float* __restrict__ sidx) {
  const int b = (int)blockIdx.x;     // 0..3
  const int m = (int)threadIdx.x;    // 0..255
  const int td = m >> 7;             // time segment 0/1
  const int i  = m & 127;
  const int li = out_idx[(b * 2 + td) * KSEL + i];
  const int gi = li + td * NPTS;
  sidx[b * 256 + m] = (float)gi;
  const float* src = x + ((size_t)b * THW + gi) * CDIM;
  float* dst = patches + ((size_t)b * 256 + m) * 32;
#pragma unroll
  for (int c = 0; c < 32; ++c) dst[c] = src[c];   // first C-3 channels
}

extern "C" void kernel_launch(void* const* d_in, const int* in_sizes, int n_in,
                              void* d_out, int out_size, void* d_ws, size_t ws_size,
                              hipStream_t stream) {
  const float* x    = (const float*)d_in[0];
  const int*   init = (const int*)d_in[1];
  (void)in_sizes; (void)n_in; (void)out_size; (void)ws_size;

  // ws layout: slots [BT*KSEL*BPS u64] | idx [BT*KSEL int]
  unsigned long long* slots = (unsigned long long*)d_ws;
  const size_t slots_bytes = (size_t)BT * KSEL * BPS * sizeof(unsigned long long);
  int* idx = (int*)((char*)d_ws + slots_bytes);

  float* patches = (float*)d_out;
  float* sidx    = patches + (size_t)4 * 256 * 32;

  hipMemsetAsync(d_ws, 0, slots_bytes, stream);   // zero sync slots per launch

  void* kargs[] = { (void*)&x, (void*)&init, (void*)&idx, (void*)&slots };
  hipLaunchCooperativeKernel((const void*)fps_kernel, dim3(NB), dim3(BLK),
                             kargs, 0, stream);

  hipLaunchKernelGGL(gather_kernel, dim3(4), dim3(256), 0, stream,
                     x, idx, patches, sidx);
}

// Round 14
// 218.453 us; speedup vs baseline: 1.2069x; 1.0315x over previous
//
#include <hip/hip_runtime.h>

// KCenterSampler FPS — R12 + same-XCD L2 probe channel + fused gather.
//
// Probe channel: publisher PLAIN-stores the winner key (writeback -> shared
// XCD L2) in addition to the proven agent-scope LLC slot. Pollers sample the
// probe with sc0 loads (L1-bypass, L2-serve, ~300cy RT) 3x per LLC sample.
// All poll loads are SELF-CONTAINED (issue+vmcnt(0) in one asm block) so the
// in-order vmcnt counter never mixes latencies. Per-word max-merge of both
// channels (slots write-once 0->key; both words nonzero when written).
// Progress guaranteed by the LLC channel alone (R4-proven). Probe slots are
// plain-store-zeroed in-kernel (fixes stale-L2 across replays), sequenced by
// a per-segment ready-barrier on LLC slot row 0 (R4 mechanism).
// R6/R10 lesson baked in: sc0 STOREs stream past L2 (blind); plain stores
// allocate. sc0 loads bypass L1 only.
//
// Gather fused: sub==0 blocks write sidx + the 32-float patch row per step
// (x row = local-L2 hit); gather_kernel and out_idx are gone.
//
// Everything else identical to R12 (passed, absmax 0): 8 segs x 16 blocks
// cooperative, b=bid&7 (round-robin -> same XCD), coords/sq/dist in VGPRs
// (waves_per_eu(1,1) + asm launder, VGPR=132), DPP reductions, packed
// (monotone-dist, NPTS-j) u64 keys, first-index tie-break.

#define NPTS 6272
#define CDIM 35
#define BT   8
#define KSEL 128
#define THW  12544
#define BPS  16                  // blocks per segment
#define PPB  392                 // points per block
#define BLK  256
#define NB   (BT * BPS)          // 128 blocks
#define TAILN (PPB - BLK)        // 136: threads owning a 2nd point

__device__ __forceinline__ unsigned long long key_of(float v, int j) {
  unsigned int u = __float_as_uint(v);
  u = (u & 0x80000000u) ? ~u : (u | 0x80000000u);   // monotone float->uint
  return ((unsigned long long)u << 32) | (unsigned int)(NPTS - j); // both words !=0
}
__device__ __forceinline__ unsigned long long kmax(unsigned long long a,
                                                   unsigned long long b) {
  return a > b ? a : b;
}
// per-word max merge (each word is write-once 0->nonzero; tearing safe)
__device__ __forceinline__ unsigned long long merge64(unsigned long long a,
                                                      unsigned long long t) {
  unsigned int lo = (unsigned int)a > (unsigned int)t ? (unsigned int)a : (unsigned int)t;
  unsigned int ah = (unsigned int)(a >> 32), th = (unsigned int)(t >> 32);
  unsigned int hi = ah > th ? ah : th;
  return ((unsigned long long)hi << 32) | lo;
}

// one DPP max step on a u64 key
template <int CTRL, int RMASK, bool BC>
__device__ __forceinline__ unsigned long long dpp_kmax(unsigned long long k) {
  unsigned int lo = (unsigned int)k, hi = (unsigned int)(k >> 32);
  unsigned int tlo = (unsigned int)__builtin_amdgcn_update_dpp(0, (int)lo, CTRL, RMASK, 0xF, BC);
  unsigned int thi = (unsigned int)__builtin_amdgcn_update_dpp(0, (int)hi, CTRL, RMASK, 0xF, BC);
  unsigned long long t = ((unsigned long long)thi << 32) | tlo;
  return kmax(k, t);
}
__device__ __forceinline__ unsigned long long wave_kmax64(unsigned long long k) {
  k = dpp_kmax<0x111, 0xF, true >(k);
  k = dpp_kmax<0x112, 0xF, true >(k);
  k = dpp_kmax<0x114, 0xF, true >(k);
  k = dpp_kmax<0x118, 0xF, true >(k);
  k = dpp_kmax<0x142, 0xA, false>(k);
  k = dpp_kmax<0x143, 0xC, false>(k);
  unsigned int rlo = (unsigned int)__builtin_amdgcn_readlane((int)(unsigned int)k, 63);
  unsigned int rhi = (unsigned int)__builtin_amdgcn_readlane((int)(k >> 32), 63);
  return ((unsigned long long)rhi << 32) | rlo;
}
__device__ __forceinline__ unsigned long long row16_kmax(unsigned long long k) {
  k = dpp_kmax<0x111, 0xF, true>(k);
  k = dpp_kmax<0x112, 0xF, true>(k);
  k = dpp_kmax<0x114, 0xF, true>(k);
  k = dpp_kmax<0x118, 0xF, true>(k);
  unsigned int rlo = (unsigned int)__builtin_amdgcn_readlane((int)(unsigned int)k, 15);
  unsigned int rhi = (unsigned int)__builtin_amdgcn_readlane((int)(k >> 32), 15);
  return ((unsigned long long)rhi << 32) | rlo;
}

// self-contained loads (issue + wait inside one asm block; "=&v" mandatory)
__device__ __forceinline__ unsigned long long load_l2(const unsigned long long* p) {
  unsigned long long r;
  asm volatile("global_load_dwordx2 %0, %1, off sc0\n\ts_waitcnt vmcnt(0)"
               : "=&v"(r) : "v"(p) : "memory");
  return r;
}
__device__ __forceinline__ unsigned long long load_llc(const unsigned long long* p) {
  unsigned long long r;
  asm volatile("global_load_dwordx2 %0, %1, off sc0 sc1\n\ts_waitcnt vmcnt(0)"
               : "=&v"(r) : "v"(p) : "memory");
  return r;
}
__device__ __forceinline__ void store_plain(unsigned long long* p, unsigned long long v) {
  asm volatile("global_store_dwordx2 %0, %1, off" :: "v"(p), "v"(v) : "memory");
}

__global__ __attribute__((amdgpu_waves_per_eu(1, 1))) __launch_bounds__(BLK)
void fps_kernel(const float* __restrict__ x,
                const int* __restrict__ init_,
                float* __restrict__ patches,
                float* __restrict__ sidx,
                unsigned long long* __restrict__ slots,
                unsigned long long* __restrict__ probe) {
  __shared__ unsigned long long wk[4];
  __shared__ int far_s;

  const int bid  = (int)blockIdx.x;
  const int b    = bid & 7;            // segment: round-robin -> same XCD
  const int sub  = bid >> 3;           // sub-block 0..15 within segment
  const int tid  = (int)threadIdx.x;
  const int lane = tid & 63;
  const int wid  = tid >> 6;
  const int j0   = sub * PPB;
  const int td   = b & 1;              // time slice within batch
  const float* xg = x + (size_t)b * NPTS * CDIM;
  unsigned long long* seg = slots + (size_t)b * KSEL * BPS;
  unsigned long long* prb = probe + (size_t)b * KSEL * BPS;

  // ---- zero own probe slots through the L2 path (plain stores) ----
  if (tid >= 1 && tid < KSEL)
    store_plain(&prb[tid * BPS + sub], 0ull);

  // ---- one-time load: coords -> VGPRs (laundered), sq sequential ----
  float xr0[CDIM], xr1[CDIM];
  float sqr0, sqr1, df0, df1;
  {
    const float* src0 = xg + (size_t)(j0 + tid) * CDIM;
    float acc = 0.0f;
    {
#pragma clang fp contract(off)
#pragma unroll
      for (int c = 0; c < CDIM; ++c) { float v = src0[c]; xr0[c] = v; acc = acc + v * v; }
    }
    sqr0 = acc; df0 = 50000.0f;
    sqr1 = 0.0f; df1 = 50000.0f;
#pragma unroll
    for (int c = 0; c < CDIM; ++c) xr1[c] = 0.0f;
    if (tid < TAILN) {
      const float* src1 = xg + (size_t)(j0 + BLK + tid) * CDIM;
      float acc1 = 0.0f;
      {
#pragma clang fp contract(off)
#pragma unroll
        for (int c = 0; c < CDIM; ++c) { float v = src1[c]; xr1[c] = v; acc1 = acc1 + v * v; }
      }
      sqr1 = acc1;
    }
#pragma unroll
    for (int c = 0; c < CDIM; ++c) {
      asm volatile("" : "+v"(xr0[c]));
      asm volatile("" : "+v"(xr1[c]));
    }
    asm volatile("" : "+v"(sqr0));
    asm volatile("" : "+v"(sqr1));
  }

  // ---- per-segment ready-barrier on LLC slot row 0 (R4-proven path) ----
  asm volatile("s_waitcnt vmcnt(0)" ::: "memory");   // probe zeros are in L2
  if (tid == 0)
    __hip_atomic_store(&seg[sub], 1ull, __ATOMIC_RELAXED, __HIP_MEMORY_SCOPE_AGENT);
  if (tid < BPS) {
    while (__hip_atomic_load(&seg[tid], __ATOMIC_RELAXED,
                             __HIP_MEMORY_SCOPE_AGENT) == 0ull) {}
  }
  __syncthreads();

  int far;
  { int f = init_[b] % NPTS; if (f < 0) f += NPTS; far = f; }  // jnp.remainder
  if (sub == 0) {                      // fused output, row 0
    if (tid == 0) sidx[b * KSEL] = (float)(far + td * NPTS);
    if (tid < 32) patches[(size_t)(b * KSEL) * 32 + tid] = xg[(size_t)far * CDIM + tid];
  }

  // ---- 127 sequential FPS steps ----
  for (int step = 1; step < KSEL; ++step) {
    const int fu = __builtin_amdgcn_readfirstlane(far);
    const float* fx = xg + (size_t)fu * CDIM;
    float xf[CDIM];
#pragma unroll
    for (int c = 0; c < CDIM; ++c) xf[c] = fx[c];

    float sqf;
    {
#pragma clang fp contract(off)
      float a = 0.0f;
#pragma unroll
      for (int c = 0; c < CDIM; ++c) { float t = xf[c]; a = a + t * t; }
      sqf = a;
    }

    unsigned long long bk;
    {
      float dot = 0.0f;
#pragma unroll
      for (int c = 0; c < CDIM; ++c)
        dot = __builtin_fmaf(xf[c], xr0[c], dot);          // k-sequential FMA
      float d2;
      {
#pragma clang fp contract(off)
        d2 = (sqf + sqr0) - 2.0f * dot;                    // reference order
      }
      d2 = fmaxf(d2, 0.0f);
      float d = __fsqrt_rn(d2);
      const int j = j0 + tid;
      d = (j == far) ? -1.0f : d;                          // diagonal = -1
      float nd = fminf(d, df0);                            // f32 min-carry
      df0 = nd;
      bk = key_of(nd, j);
    }
    if (tid < TAILN) {
      float dot = 0.0f;
#pragma unroll
      for (int c = 0; c < CDIM; ++c)
        dot = __builtin_fmaf(xf[c], xr1[c], dot);
      float d2;
      {
#pragma clang fp contract(off)
        d2 = (sqf + sqr1) - 2.0f * dot;
      }
      d2 = fmaxf(d2, 0.0f);
      float d = __fsqrt_rn(d2);
      const int j = j0 + BLK + tid;
      d = (j == far) ? -1.0f : d;
      float nd = fminf(d, df1);
      df1 = nd;
      bk = kmax(bk, key_of(nd, j));
    }

    bk = wave_kmax64(bk);
    if (lane == 0) wk[wid] = bk;
    __syncthreads();                                       // barrier 1

    if (tid < BPS) {
      if (tid == 0) {
        unsigned long long m = kmax(kmax(wk[0], wk[1]), kmax(wk[2], wk[3]));
        store_plain(&prb[step * BPS + sub], m);            // L2 probe (fast)
        __hip_atomic_store(&seg[step * BPS + sub], m,      // LLC (guaranteed)
                           __ATOMIC_RELAXED, __HIP_MEMORY_SCOPE_AGENT);
      }
      asm volatile("" ::: "memory");
      unsigned long long k = 0ull;
      const unsigned long long* pp = &prb[step * BPS + tid];
      const unsigned long long* sp = &seg[step * BPS + tid];
      while (__any(k == 0ull)) {
#pragma unroll
        for (int q = 0; q < 3; ++q) {                      // 3 probe samples
          if (__any(k == 0ull)) {
            if (k == 0ull) k = merge64(k, load_l2(pp));
            __builtin_amdgcn_s_sleep(1);
          }
        }
        if (k == 0ull) k = merge64(k, load_llc(sp));       // LLC fallback
      }
      k = row16_kmax(k);
      if (tid == 0)
        far_s = NPTS - (int)(unsigned int)(k & 0xFFFFFFFFull);
    }
    __syncthreads();                                       // barrier 2
    far = far_s;

    if (sub == 0) {                    // fused output row `step`
      if (tid == 0) sidx[b * KSEL + step] = (float)(far + td * NPTS);
      if (tid < 32) patches[(size_t)(b * KSEL + step) * 32 + tid] =
                        xg[(size_t)far * CDIM + tid];
    }
  }
}

extern "C" void kernel_launch(void* const* d_in, const int* in_sizes, int n_in,
                              void* d_out, int out_size, void* d_ws, size_t ws_size,
                              hipStream_t stream) {
  const float* x    = (const float*)d_in[0];
  const int*   init = (const int*)d_in[1];
  (void)in_sizes; (void)n_in; (void)out_size; (void)ws_size;

  // ws layout: llc slots [BT*KSEL*BPS u64] | probe slots [same]
  const size_t arr = (size_t)BT * KSEL * BPS * sizeof(unsigned long long);
  unsigned long long* slots = (unsigned long long*)d_ws;
  unsigned long long* probe = (unsigned long long*)((char*)d_ws + arr);

  float* patches = (float*)d_out;
  float* sidx    = patches + (size_t)4 * 256 * 32;

  hipMemsetAsync(d_ws, 0, 2 * arr, stream);   // LLC-level zeros for both arrays

  void* kargs[] = { (void*)&x, (void*)&init, (void*)&patches, (void*)&sidx,
                    (void*)&slots, (void*)&probe };
  hipLaunchCooperativeKernel((const void*)fps_kernel, dim3(NB), dim3(BLK),
                             kargs, 0, stream);
}